// Round 3
// baseline (189.200 us; speedup 1.0000x reference)
//
#include <hip/hip_runtime.h>
#include <math.h>

// EdgeDetection: fused gray -> gauss3x3(sigma=0.8) -> scharr -> L2 mag, reflect-101
// Composite separable 5-tap: sx = (vert [3,10,3]*g) x (horiz [-1,0,1]*g), sy = transpose.
// R5: WAVE-STREAMING rewrite. R2 counters showed barrier convoy: grid==residency,
// all blocks phase-locked load->barrier->compute, VALU 21% / HBM 34% / LDS conflicts.
// Now: no LDS, no __syncthreads. Each wave owns a 256-wide x 8-row strip, marches
// down with a 5-row (hs,hd) register ring, RGB loaded direct from global with 2-row
// ping-pong lookahead, horizontal halo via shfl (edge lanes load 2-px halo direct).

#define IMG_H 1024
#define IMG_W 1024
#define SH 8                  // output rows per wave-strip
#define NSTRIPS (IMG_H / SH)  // 128

// 1D gaussian sigma=0.8 k=3: e=exp(-0.78125); W0=1/(1+2e), W1=e/(1+2e)
#define W0 0.52201125f
#define W1 0.23899437f
// composite smooth taps conv([3,10,3],[W1,W0,W1]):
#define AV0 0.71698311f   // 3*W1
#define AV1 3.95597745f   // 3*W0 + 10*W1
#define AV2 6.65407872f   // 10*W0 + 6*W1

typedef float vf4 __attribute__((ext_vector_type(4)));

__device__ __forceinline__ int reflect101(int v, int n) {
    v = (v < 0) ? -v : v;
    return (v >= n) ? (2 * n - 2 - v) : v;
}

struct Row {
    float4 r, g, b;                    // 4 px of each channel
    float er0, er1, eg0, eg1, eb0, eb1; // 2-px horizontal halo (edge lanes only)
};

__global__ __launch_bounds__(256)
void edge_kernel(const float* __restrict__ in, float* __restrict__ out) {
    const int lane = threadIdx.x & 63;
    const int wx   = threadIdx.x >> 6;  // 0..3, 256-px column band per wave
    // XCD-chunked swizzle: 128 strips -> 16 contiguous strips per XCD so
    // vertically-adjacent strips (shared 4-row halo) land in the same L2.
    const int bx    = blockIdx.x;
    const int strip = (bx & 7) * (NSTRIPS / 8) + (bx >> 3);
    const int b     = blockIdx.y;
    const int y0    = strip * SH;
    const int x4    = (wx * 64 + lane) * 4;

    const size_t plane = (size_t)IMG_H * IMG_W;
    const float* pr = in + (size_t)b * 3 * plane;
    const float* pg = pr + plane;
    const float* pb = pg + plane;
    float* po = out + (size_t)b * 3 * plane;

    const bool eL = (lane == 0), eR = (lane == 63);
    const bool eAny = eL || eR;
    int ex0, ex1;
    if (eL) { ex0 = reflect101(x4 - 2, IMG_W); ex1 = reflect101(x4 - 1, IMG_W); }
    else    { ex0 = reflect101(x4 + 4, IMG_W); ex1 = reflect101(x4 + 5, IMG_W); }

    float hs[5][4], hd[5][4];

    auto LOAD = [&](Row& d, int y) {
        int yy = reflect101(y, IMG_H);
        size_t ro = (size_t)yy * IMG_W;
        size_t o  = ro + x4;
        d.r = *(const float4*)(pr + o);
        d.g = *(const float4*)(pg + o);
        d.b = *(const float4*)(pb + o);
        if (eAny) {
            d.er0 = pr[ro + ex0]; d.er1 = pr[ro + ex1];
            d.eg0 = pg[ro + ex0]; d.eg1 = pg[ro + ex1];
            d.eb0 = pb[ro + ex0]; d.eb1 = pb[ro + ex1];
        }
    };

    auto HROW = [&](const Row& d, float* HS, float* HD) {
        float g0 = 0.299f * d.r.x + 0.587f * d.g.x + 0.114f * d.b.x;
        float g1 = 0.299f * d.r.y + 0.587f * d.g.y + 0.114f * d.b.y;
        float g2 = 0.299f * d.r.z + 0.587f * d.g.z + 0.114f * d.b.z;
        float g3 = 0.299f * d.r.w + 0.587f * d.g.w + 0.114f * d.b.w;
        float ge0 = 0.299f * d.er0 + 0.587f * d.eg0 + 0.114f * d.eb0;
        float ge1 = 0.299f * d.er1 + 0.587f * d.eg1 + 0.114f * d.eb1;
        // horizontal halo: G[-2],G[-1] from left lane, G[4],G[5] from right lane
        float lm2 = __shfl_up(g2, 1);
        float lm1 = __shfl_up(g3, 1);
        float rp4 = __shfl_down(g0, 1);
        float rp5 = __shfl_down(g1, 1);
        if (eL) { lm2 = ge0; lm1 = ge1; }
        if (eR) { rp4 = ge0; rp5 = ge1; }
        HS[0] = AV0 * (lm2 + g2) + AV1 * (lm1 + g1) + AV2 * g0;
        HS[1] = AV0 * (lm1 + g3) + AV1 * (g0 + g2) + AV2 * g1;
        HS[2] = AV0 * (g0 + rp4) + AV1 * (g1 + g3) + AV2 * g2;
        HS[3] = AV0 * (g1 + rp5) + AV1 * (g2 + rp4) + AV2 * g3;
        HD[0] = W1 * (g2 - lm2) + W0 * (g1 - lm1);
        HD[1] = W1 * (g3 - lm1) + W0 * (g2 - g0);
        HD[2] = W1 * (rp4 - g0) + W0 * (g3 - g1);
        HD[3] = W1 * (rp5 - g1) + W0 * (rp4 - g2);
    };

    // ---- prologue: warm the 5-row ring (rows y0-2 .. y0+1), 2-deep pipeline ----
    Row ra, rb;
    LOAD(ra, y0 - 2);
    LOAD(rb, y0 - 1);
    HROW(ra, hs[0], hd[0]); LOAD(ra, y0);
    HROW(rb, hs[1], hd[1]); LOAD(rb, y0 + 1);
    HROW(ra, hs[2], hd[2]); LOAD(ra, y0 + 2);
    HROW(rb, hs[3], hd[3]); LOAD(rb, y0 + 3);

    // ---- main: 8 output rows; input row y0+2+t arrives in ping-pong buffer ----
    #pragma unroll
    for (int t = 0; t < SH; ++t) {
        Row& rc = (t & 1) ? rb : ra;          // static under full unroll
        HROW(rc, hs[(t + 4) % 5], hd[(t + 4) % 5]);
        if (t <= SH - 3) LOAD(rc, y0 + 4 + t); // prefetch 2 rows ahead
        const int i0 = t % 5, i1 = (t + 1) % 5, i2 = (t + 2) % 5,
                  i3 = (t + 3) % 5, i4 = (t + 4) % 5;
        vf4 mag;
        #pragma unroll
        for (int k = 0; k < 4; ++k) {
            float sx = AV0 * (hd[i0][k] + hd[i4][k]) + AV1 * (hd[i1][k] + hd[i3][k]) + AV2 * hd[i2][k];
            float sy = W1 * (hs[i4][k] - hs[i0][k]) + W0 * (hs[i3][k] - hs[i1][k]);
            mag[k] = sqrtf(sx * sx + sy * sy);
        }
        size_t o = (size_t)(y0 + t) * IMG_W + x4;
        __builtin_nontemporal_store(mag, (vf4*)(po + o));
        __builtin_nontemporal_store(mag, (vf4*)(po + o + plane));
        __builtin_nontemporal_store(mag, (vf4*)(po + o + 2 * plane));
    }
}

extern "C" void kernel_launch(void* const* d_in, const int* in_sizes, int n_in,
                              void* d_out, int out_size, void* d_ws, size_t ws_size,
                              hipStream_t stream) {
    const float* in = (const float*)d_in[0];
    float* out = (float*)d_out;
    const int B = in_sizes[0] / (3 * IMG_H * IMG_W);
    dim3 grid(NSTRIPS, B);
    edge_kernel<<<grid, dim3(256), 0, stream>>>(in, out);
}

// Round 6
// 175.419 us; speedup vs baseline: 1.0786x; 1.0786x over previous
//
#include <hip/hip_runtime.h>
#include <math.h>

// EdgeDetection: fused gray -> gauss3x3(sigma=0.8) -> scharr -> L2 mag, reflect-101
// Composite separable 5-tap: sx = (vert [3,10,3]*g) x (horiz [-1,0,1]*g), sy = transpose.
// R6: async-staging rewrite. R2 counters (VGPR=48) proved compiler serialized the
// VGPR staging pipeline; R5 proved wave-streaming starves TLP (occ 23%). Now:
// global_load_lds (16B, zero VGPR round-trip, 9 async loads/thread in flight),
// raw RGB staged to LDS, in-place gray convert (own-slot only, race-free),
// 128x16 tile -> 36.9KB LDS -> 4 blocks/CU, 4096 blocks = 4 residency generations
// (decorrelates phases; kills the R2 barrier convoy). x-edge reflect in registers.
// R7/R8: identical resubmits (R6 never ran - broker acquisition timeouts).

#define IMG_H 1024
#define IMG_W 1024
#define TW 128
#define TH 16
#define GCOLS 136            // staged cols x0-4 .. x0+131 (34 float4, 16B-aligned rows)
#define ITEMS 768            // float4 items staged per channel: 680 real (20 rows x 34) + pad to 3*256

// 1D gaussian sigma=0.8 k=3: e=exp(-0.78125); W0=1/(1+2e), W1=e/(1+2e)
#define W0 0.52201125f
#define W1 0.23899437f
// composite smooth taps conv([3,10,3],[W1,W0,W1]):
#define AV0 0.71698311f   // 3*W1
#define AV1 3.95597745f   // 3*W0 + 10*W1
#define AV2 6.65407872f   // 10*W0 + 6*W1

typedef float vf4 __attribute__((ext_vector_type(4)));
#define AS_GLOBAL const __attribute__((address_space(1))) void*
#define AS_LDS __attribute__((address_space(3))) void*

__device__ __forceinline__ int reflect101(int v, int n) {
    v = (v < 0) ? -v : v;
    return (v >= n) ? (2 * n - 2 - v) : v;
}

__global__ __launch_bounds__(256, 4)
void edge_kernel(const float* __restrict__ in, float* __restrict__ out) {
    __shared__ __align__(16) float sR[ITEMS * 4];
    __shared__ __align__(16) float sG[ITEMS * 4];
    __shared__ __align__(16) float sB[ITEMS * 4];

    const int tid = threadIdx.x;
    const int bx = blockIdx.x, by = blockIdx.y, b = blockIdx.z;
    const int x0 = bx * TW, y0 = by * TH;

    const size_t plane = (size_t)IMG_H * IMG_W;
    const float* pr = in + (size_t)b * 3 * plane;
    const float* pg = pr + plane;
    const float* pb = pg + plane;

    // ---- stage raw RGB via async global->LDS, 9 loads/thread, no guards ----
    #pragma unroll
    for (int k = 0; k < 3; ++k) {
        const int item = tid + k * 256;       // all 768 lanes-slots always active
        const int gy = item / 34;             // rows 0..19 real, 20..22 junk pad
        const int g4 = (item - gy * 34) * 4;
        const int y = reflect101(y0 - 2 + gy, IMG_H);
        int x = x0 - 4 + g4;
        x = x < 0 ? 0 : (x > IMG_W - 4 ? IMG_W - 4 : x);  // clamp; edges fixed in regs later
        const size_t o = (size_t)y * IMG_W + x;
        __builtin_amdgcn_global_load_lds((AS_GLOBAL)(pr + o), (AS_LDS)&sR[item * 4], 16, 0, 0);
        __builtin_amdgcn_global_load_lds((AS_GLOBAL)(pg + o), (AS_LDS)&sG[item * 4], 16, 0, 0);
        __builtin_amdgcn_global_load_lds((AS_GLOBAL)(pb + o), (AS_LDS)&sB[item * 4], 16, 0, 0);
    }
    __syncthreads();

    // ---- in-place gray convert: each thread touches only its own 16B slot ----
    #pragma unroll
    for (int k = 0; k < 3; ++k) {
        const int i4 = (tid + k * 256) * 4;
        float4 r = *(const float4*)&sR[i4];
        float4 g = *(const float4*)&sG[i4];
        float4 bb = *(const float4*)&sB[i4];
        float4 gr;
        gr.x = 0.299f * r.x + 0.587f * g.x + 0.114f * bb.x;
        gr.y = 0.299f * r.y + 0.587f * g.y + 0.114f * bb.y;
        gr.z = 0.299f * r.z + 0.587f * g.z + 0.114f * bb.z;
        gr.w = 0.299f * r.w + 0.587f * g.w + 0.114f * bb.w;
        *(float4*)&sR[i4] = gr;
    }
    __syncthreads();

    // ---- compute: thread = 4 cols x 2 rows; 6 hrows into hs/hd, then 2 outputs ----
    const int tx = tid & 31;        // col group: cols c4..c4+3
    const int tyg = tid >> 5;       // 0..7
    const int c4 = tx * 4;
    const int r0 = tyg * 2;         // output rows y0+r0, y0+r0+1
    const bool eBL = (bx == 0) && (tx == 0);
    const bool eBR = (bx == (IMG_W / TW - 1)) && (tx == 31);

    float hs[6][4], hd[6][4];
    #pragma unroll
    for (int s = 0; s < 6; ++s) {
        const float* row = &sR[(r0 + s) * GCOLS + c4];
        float4 ga = *(const float4*)(row);
        float4 gb = *(const float4*)(row + 4);
        float4 gc = *(const float4*)(row + 8);
        float g[12] = {ga.x, ga.y, ga.z, ga.w, gb.x, gb.y, gb.z, gb.w,
                       gc.x, gc.y, gc.z, gc.w};
        // reflect-101 x-edge fixup in registers (cols -2,-1 / 1024,1025)
        if (eBL) { g[2] = g[6]; g[3] = g[5]; }
        if (eBR) { g[8] = g[6]; g[9] = g[5]; }
        #pragma unroll
        for (int k = 0; k < 4; ++k) {
            hs[s][k] = AV0 * (g[k+2] + g[k+6]) + AV1 * (g[k+3] + g[k+5]) + AV2 * g[k+4];
            hd[s][k] = W1 * (g[k+6] - g[k+2]) + W0 * (g[k+5] - g[k+3]);
        }
    }

    float* po = out + (size_t)b * 3 * plane;
    #pragma unroll
    for (int t = 0; t < 2; ++t) {
        vf4 mag;
        #pragma unroll
        for (int k = 0; k < 4; ++k) {
            float sx = AV0 * (hd[t][k] + hd[t+4][k]) + AV1 * (hd[t+1][k] + hd[t+3][k]) + AV2 * hd[t+2][k];
            float sy = W1 * (hs[t+4][k] - hs[t][k]) + W0 * (hs[t+3][k] - hs[t+1][k]);
            mag[k] = sqrtf(sx * sx + sy * sy);
        }
        const size_t o = (size_t)(y0 + r0 + t) * IMG_W + (x0 + c4);
        __builtin_nontemporal_store(mag, (vf4*)(po + o));
        __builtin_nontemporal_store(mag, (vf4*)(po + o + plane));
        __builtin_nontemporal_store(mag, (vf4*)(po + o + 2 * plane));
    }
}

extern "C" void kernel_launch(void* const* d_in, const int* in_sizes, int n_in,
                              void* d_out, int out_size, void* d_ws, size_t ws_size,
                              hipStream_t stream) {
    const float* in = (const float*)d_in[0];
    float* out = (float*)d_out;
    const int B = in_sizes[0] / (3 * IMG_H * IMG_W);
    dim3 grid(IMG_W / TW, IMG_H / TH, B);
    edge_kernel<<<grid, dim3(256), 0, stream>>>(in, out);
}